// Round 14
// baseline (96.155 us; speedup 1.0000x reference)
//
#include <hip/hip_runtime.h>

#define BB 32
#define CC 3
#define HH 128
#define WW 128
#define NN 1024
#define KK (CC*HH*WW)        // 49152
#define NROWS (CC*HH)        // 384
#define KSR NROWS            // 384 split-K groups (1 row each)
#define BH 16                // batches per block
#define BSPLIT (BB/BH)       // 2
#define WCH 8                // w-columns per register chunk (covers HBM latency)
#define NCH (WW/WCH)         // 16 chunks per row
#define SG 8                 // s-groups in fused reduce
#define STEP (1.0f/127.0f)

// ---- per-neuron normalization scale: scale[n] = sqrt(H*W/(Sx*Sy)) ----
__global__ void scale_kernel(const float* __restrict__ mu_x,
                             const float* __restrict__ mu_y,
                             const float* __restrict__ sigma_x,
                             const float* __restrict__ sigma_y,
                             float* __restrict__ scale) {
    int n = blockIdx.x * blockDim.x + threadIdx.x;
    if (n >= NN) return;
    float mux = mu_x[n], muy = mu_y[n];
    float isx = 1.0f / sigma_x[n], isy = 1.0f / sigma_y[n];
    float Sx = 0.f, Sy = 0.f;
    for (int i = 0; i < WW; ++i) {
        float dx = (i * STEP - mux) * isx;
        Sx += __expf(-dx * dx);
        float dy = (i * STEP - muy) * isy;
        Sy += __expf(-dy * dy);
    }
    scale[n] = sqrtf((float)(HH * WW) / (Sx * Sy));
}

// ---- transpose x[B,K] -> xT[K,B] (proven R1 kernel) ----
__global__ void xpose_kernel(const float* __restrict__ x, float* __restrict__ xT) {
    __shared__ float tile[64][BB + 1];
    int k0 = blockIdx.x * 64;
    int lane = threadIdx.x & 63;   // k within tile
    int bgrp = threadIdx.x >> 6;   // 0..3
#pragma unroll
    for (int i = 0; i < 8; ++i) {
        int b = bgrp * 8 + i;
        tile[lane][b] = x[(size_t)b * KK + k0 + lane];
    }
    __syncthreads();
    int b = threadIdx.x & 31;
    int kk0 = threadIdx.x >> 5;    // 0..7
#pragma unroll
    for (int i = 0; i < 8; ++i) {
        int kk = i * 8 + kk0;
        xT[(size_t)(k0 + kk) * BB + b] = tile[kk][b];
    }
}

// ---- main v10: R8 structure, WCH=8 (prefetch covers HBM latency) ----
// block = (row g, batch-half b0); wave owns a 256-n slice; lane owns 4 n.
__global__ __launch_bounds__(256) void main_pipe(
    const float* __restrict__ weights,
    const float* __restrict__ xT,
    const float* __restrict__ scale,
    const float* __restrict__ mu_x, const float* __restrict__ mu_y,
    const float* __restrict__ sigma_x, const float* __restrict__ sigma_y,
    float* __restrict__ part)
{
    const int tid  = threadIdx.x;
    const int wv   = tid >> 6;
    const int lane = tid & 63;

    // XCD swizzle: the 2 batch-half siblings of a row -> same XCD, adjacent.
    const int d    = blockIdx.x;             // 0..767
    const int xcd  = d & 7;
    const int slot = d >> 3;                 // 0..95
    const int g    = xcd * (KSR / 8) + (slot >> 1);   // 0..383
    const int b0   = (slot & 1) * BH;
    const int r    = g;
    const int h    = r & (HH - 1);
    const int nq   = wv * 64 + lane;         // float4 index into n-arrays

    const float4 mux = ((const float4*)mu_x)[nq];
    const float4 sx4 = ((const float4*)sigma_x)[nq];
    const float4 muy = ((const float4*)mu_y)[nq];
    const float4 sy4 = ((const float4*)sigma_y)[nq];
    const float4 sc4 = ((const float4*)scale)[nq];

    float4 ax, axs, Bf, gyrow;
    ax.x = -0.5f/(sx4.x*sx4.x); ax.y = -0.5f/(sx4.y*sx4.y);
    ax.z = -0.5f/(sx4.z*sx4.z); ax.w = -0.5f/(sx4.w*sx4.w);
    axs.x = ax.x*STEP; axs.y = ax.y*STEP; axs.z = ax.z*STEP; axs.w = ax.w*STEP;
    Bf.x = __expf(2.f*axs.x*STEP); Bf.y = __expf(2.f*axs.y*STEP);
    Bf.z = __expf(2.f*axs.z*STEP); Bf.w = __expf(2.f*axs.w*STEP);
    {   // gy[h]*scale inline
        const float hp = h * STEP;
        float ayc, dd;
        ayc = -0.5f/(sy4.x*sy4.x); dd = hp-muy.x; gyrow.x = __expf(ayc*dd*dd)*sc4.x;
        ayc = -0.5f/(sy4.y*sy4.y); dd = hp-muy.y; gyrow.y = __expf(ayc*dd*dd)*sc4.y;
        ayc = -0.5f/(sy4.z*sy4.z); dd = hp-muy.z; gyrow.z = __expf(ayc*dd*dd)*sc4.z;
        ayc = -0.5f/(sy4.w*sy4.w); dd = hp-muy.w; gyrow.w = __expf(ayc*dd*dd)*sc4.w;
    }

    const float* wbase = weights + (size_t)r * WW * NN + nq * 4;
    const float4* xr4  = (const float4*)xT + (size_t)r * (WW * BB / 4) + (b0 >> 2);
    // per w: xr4[w*8 + q], q = 0..3 (16 batches, block-uniform address)

    float4 wR[2][WCH];                        // double-buffered weight quads
#define WLOAD(BUF, C)                                                   \
    {                                                                   \
        _Pragma("unroll")                                               \
        for (int i = 0; i < WCH; ++i)                                   \
            wR[BUF][i] = *(const float4*)(wbase + (size_t)((C)*WCH + i) * NN); \
    }

    float4 acc[BH];
#pragma unroll
    for (int b = 0; b < BH; ++b) acc[b] = make_float4(0.f, 0.f, 0.f, 0.f);

    float4 g4, r4;
    auto resync = [&](int w0) {              // fresh exps, span <= 16 w
        const float w0s = (float)w0 * STEP;
        float dd;
        dd = w0s - mux.x; g4.x = __expf(ax.x*dd*dd)*gyrow.x; r4.x = __expf(axs.x*(2.f*dd+STEP));
        dd = w0s - mux.y; g4.y = __expf(ax.y*dd*dd)*gyrow.y; r4.y = __expf(axs.y*(2.f*dd+STEP));
        dd = w0s - mux.z; g4.z = __expf(ax.z*dd*dd)*gyrow.z; r4.z = __expf(axs.z*(2.f*dd+STEP));
        dd = w0s - mux.w; g4.w = __expf(ax.w*dd*dd)*gyrow.w; r4.w = __expf(axs.w*(2.f*dd+STEP));
    };

#define FMAQ(XQ, A0)                                                    \
    {                                                                   \
        acc[A0+0].x = fmaf(XQ.x, t.x, acc[A0+0].x);                     \
        acc[A0+0].y = fmaf(XQ.x, t.y, acc[A0+0].y);                     \
        acc[A0+0].z = fmaf(XQ.x, t.z, acc[A0+0].z);                     \
        acc[A0+0].w = fmaf(XQ.x, t.w, acc[A0+0].w);                     \
        acc[A0+1].x = fmaf(XQ.y, t.x, acc[A0+1].x);                     \
        acc[A0+1].y = fmaf(XQ.y, t.y, acc[A0+1].y);                     \
        acc[A0+1].z = fmaf(XQ.y, t.z, acc[A0+1].z);                     \
        acc[A0+1].w = fmaf(XQ.y, t.w, acc[A0+1].w);                     \
        acc[A0+2].x = fmaf(XQ.z, t.x, acc[A0+2].x);                     \
        acc[A0+2].y = fmaf(XQ.z, t.y, acc[A0+2].y);                     \
        acc[A0+2].z = fmaf(XQ.z, t.z, acc[A0+2].z);                     \
        acc[A0+2].w = fmaf(XQ.z, t.w, acc[A0+2].w);                     \
        acc[A0+3].x = fmaf(XQ.w, t.x, acc[A0+3].x);                     \
        acc[A0+3].y = fmaf(XQ.w, t.y, acc[A0+3].y);                     \
        acc[A0+3].z = fmaf(XQ.w, t.z, acc[A0+3].z);                     \
        acc[A0+3].w = fmaf(XQ.w, t.w, acc[A0+3].w);                     \
    }

#define CHUNK(BUF, C)                                                   \
    {                                                                   \
        resync((C) * WCH);                                              \
        _Pragma("unroll")                                               \
        for (int i = 0; i < WCH; ++i) {                                 \
            const int w = (C) * WCH + i;                                \
            const float4 xq0 = xr4[w*8 + 0];                            \
            const float4 xq1 = xr4[w*8 + 1];                            \
            const float4 xq2 = xr4[w*8 + 2];                            \
            const float4 xq3 = xr4[w*8 + 3];                            \
            const float4 wt  = wR[BUF][i];                              \
            float4 t;                                                   \
            t.x = g4.x * wt.x; t.y = g4.y * wt.y;                       \
            t.z = g4.z * wt.z; t.w = g4.w * wt.w;                       \
            FMAQ(xq0, 0)                                                \
            FMAQ(xq1, 4)                                                \
            FMAQ(xq2, 8)                                                \
            FMAQ(xq3, 12)                                               \
            g4.x *= r4.x; g4.y *= r4.y; g4.z *= r4.z; g4.w *= r4.w;     \
            r4.x *= Bf.x; r4.y *= Bf.y; r4.z *= Bf.z; r4.w *= Bf.w;     \
        }                                                               \
    }

    WLOAD(0, 0);
    for (int c = 0; c < NCH; c += 2) {
        WLOAD(1, c + 1);                     // prefetch next chunk (1280 own-cyc ahead)
        CHUNK(0, c);                         // compute current
        if (c + 2 < NCH) WLOAD(0, c + 2);
        CHUNK(1, c + 1);
    }
#undef CHUNK
#undef FMAQ
#undef WLOAD

    // coalesced float4 stores into this block's private partial slice
    float* pp = part + ((size_t)g * BB + b0) * NN + (tid << 2);
#pragma unroll
    for (int b = 0; b < BH; ++b)
        *(float4*)(pp + (size_t)b * NN) = acc[b];
}

// ---- fused reduce: out[cell] = sum over 384 slices, one kernel ----
// 256 blocks x 256 threads; block owns 32 cell-quads; thread sums 48 slices.
__global__ __launch_bounds__(256) void reduce_kernel(const float* __restrict__ part,
                                                     float* __restrict__ out) {
    __shared__ float4 buf[SG][32];
    const int t    = threadIdx.x;
    const int qi   = t & 31;                  // quad within block
    const int sgrp = t >> 5;                  // 0..7
    const int cq   = blockIdx.x * 32 + qi;    // 0..8191 cell-quads
    const int s0   = sgrp * (KSR / SG);       // 48 slices per group
    float4 a = make_float4(0.f, 0.f, 0.f, 0.f);
#pragma unroll 6
    for (int s = 0; s < KSR / SG; ++s) {
        const float4 v = *(const float4*)(part + (size_t)(s0 + s) * (BB * NN) + cq * 4);
        a.x += v.x; a.y += v.y; a.z += v.z; a.w += v.w;
    }
    buf[sgrp][qi] = a;
    __syncthreads();
    if (t < 32) {
        float4 r = buf[0][t];
#pragma unroll
        for (int sgi = 1; sgi < SG; ++sgi) {
            const float4 v = buf[sgi][t];
            r.x += v.x; r.y += v.y; r.z += v.z; r.w += v.w;
        }
        *(float4*)(out + (size_t)(blockIdx.x * 32 + t) * 4) = r;
    }
}

// ---- fallback (atomic, self-contained) — proven R3 structure ----
__global__ __launch_bounds__(256) void main_fallback(
    const float* __restrict__ weights,
    const float* __restrict__ x,
    const float* __restrict__ mu_x, const float* __restrict__ mu_y,
    const float* __restrict__ sigma_x, const float* __restrict__ sigma_y,
    float* __restrict__ dst)
{
    __shared__ float tile[2][WW][8];
    const int tid = threadIdx.x;
    const int g   = blockIdx.x;
    const int b0  = blockIdx.y * 8;
    const int r0  = g * 2;

    {
        const int b = tid & 7;
        const int c = tid >> 3;
        const float* xp = x + (size_t)(b0 + b) * KK + (size_t)r0 * WW + c * 8;
        const float4 v0 = ((const float4*)xp)[0];
        const float4 v1 = ((const float4*)xp)[1];
        const int row = (c * 8) >> 7;
        const int w   = (c * 8) & (WW - 1);
        tile[row][w+0][b] = v0.x; tile[row][w+1][b] = v0.y;
        tile[row][w+2][b] = v0.z; tile[row][w+3][b] = v0.w;
        tile[row][w+4][b] = v1.x; tile[row][w+5][b] = v1.y;
        tile[row][w+6][b] = v1.z; tile[row][w+7][b] = v1.w;
    }

    float4 mux4 = ((const float4*)mu_x)[tid];
    float4 muy4 = ((const float4*)mu_y)[tid];
    float4 sx4  = ((const float4*)sigma_x)[tid];
    float4 sy4  = ((const float4*)sigma_y)[tid];
    float4 ax4, ay4, sc4;
    ax4.x=-0.5f/(sx4.x*sx4.x); ax4.y=-0.5f/(sx4.y*sx4.y);
    ax4.z=-0.5f/(sx4.z*sx4.z); ax4.w=-0.5f/(sx4.w*sx4.w);
    ay4.x=-0.5f/(sy4.x*sy4.x); ay4.y=-0.5f/(sy4.y*sy4.y);
    ay4.z=-0.5f/(sy4.z*sy4.z); ay4.w=-0.5f/(sy4.w*sy4.w);
    {
        float Sx[4]={0,0,0,0}, Sy[4]={0,0,0,0};
        for (int i = 0; i < WW; ++i) {
            float pp = i * STEP, dd;
            dd=pp-mux4.x; Sx[0]+=__expf(2.f*ax4.x*dd*dd);
            dd=pp-mux4.y; Sx[1]+=__expf(2.f*ax4.y*dd*dd);
            dd=pp-mux4.z; Sx[2]+=__expf(2.f*ax4.z*dd*dd);
            dd=pp-mux4.w; Sx[3]+=__expf(2.f*ax4.w*dd*dd);
            dd=pp-muy4.x; Sy[0]+=__expf(2.f*ay4.x*dd*dd);
            dd=pp-muy4.y; Sy[1]+=__expf(2.f*ay4.y*dd*dd);
            dd=pp-muy4.z; Sy[2]+=__expf(2.f*ay4.z*dd*dd);
            dd=pp-muy4.w; Sy[3]+=__expf(2.f*ay4.w*dd*dd);
        }
        sc4.x = sqrtf((float)(HH*WW)/(Sx[0]*Sy[0]));
        sc4.y = sqrtf((float)(HH*WW)/(Sx[1]*Sy[1]));
        sc4.z = sqrtf((float)(HH*WW)/(Sx[2]*Sy[2]));
        sc4.w = sqrtf((float)(HH*WW)/(Sx[3]*Sy[3]));
    }
    __syncthreads();

    float acc[8][4];
#pragma unroll
    for (int b = 0; b < 8; ++b)
        acc[b][0] = acc[b][1] = acc[b][2] = acc[b][3] = 0.f;

#pragma unroll
    for (int rr = 0; rr < 2; ++rr) {
        const int rrow = r0 + rr;
        const int hh = rrow & (HH - 1);
        float4 gys;
        {
            float hp = hh * STEP, dd;
            dd=hp-muy4.x; gys.x = __expf(ay4.x*dd*dd) * sc4.x;
            dd=hp-muy4.y; gys.y = __expf(ay4.y*dd*dd) * sc4.y;
            dd=hp-muy4.z; gys.z = __expf(ay4.z*dd*dd) * sc4.z;
            dd=hp-muy4.w; gys.w = __expf(ay4.w*dd*dd) * sc4.w;
        }
        const float4* wp = (const float4*)(weights + (size_t)rrow * WW * NN) + tid;
        float racc[8][4];
#pragma unroll
        for (int b = 0; b < 8; ++b)
            racc[b][0] = racc[b][1] = racc[b][2] = racc[b][3] = 0.f;
        for (int w = 0; w < WW; ++w) {
            const float4 wt = wp[(size_t)w * (NN/4)];
            float pp = w * STEP, dd;
            float4 t;
            dd=pp-mux4.x; t.x = __expf(ax4.x*dd*dd) * wt.x;
            dd=pp-mux4.y; t.y = __expf(ax4.y*dd*dd) * wt.y;
            dd=pp-mux4.z; t.z = __expf(ax4.z*dd*dd) * wt.z;
            dd=pp-mux4.w; t.w = __expf(ax4.w*dd*dd) * wt.w;
            const float4* trp = (const float4*)&tile[rr][w][0];
            float xs[8];
            ((float4*)xs)[0] = trp[0]; ((float4*)xs)[1] = trp[1];
#pragma unroll
            for (int b = 0; b < 8; ++b) {
                racc[b][0] = fmaf(xs[b], t.x, racc[b][0]);
                racc[b][1] = fmaf(xs[b], t.y, racc[b][1]);
                racc[b][2] = fmaf(xs[b], t.z, racc[b][2]);
                racc[b][3] = fmaf(xs[b], t.w, racc[b][3]);
            }
        }
#pragma unroll
        for (int b = 0; b < 8; ++b) {
            acc[b][0] = fmaf(gys.x, racc[b][0], acc[b][0]);
            acc[b][1] = fmaf(gys.y, racc[b][1], acc[b][1]);
            acc[b][2] = fmaf(gys.z, racc[b][2], acc[b][2]);
            acc[b][3] = fmaf(gys.w, racc[b][3], acc[b][3]);
        }
    }

    float* op = dst + (size_t)b0 * NN + tid * 4;
#pragma unroll
    for (int b = 0; b < 8; ++b) {
        atomicAdd(op + (size_t)b * NN + 0, acc[b][0]);
        atomicAdd(op + (size_t)b * NN + 1, acc[b][1]);
        atomicAdd(op + (size_t)b * NN + 2, acc[b][2]);
        atomicAdd(op + (size_t)b * NN + 3, acc[b][3]);
    }
}

extern "C" void kernel_launch(void* const* d_in, const int* in_sizes, int n_in,
                              void* d_out, int out_size, void* d_ws, size_t ws_size,
                              hipStream_t stream) {
    const float* x       = (const float*)d_in[0];
    const float* mu_x    = (const float*)d_in[1];
    const float* mu_y    = (const float*)d_in[2];
    const float* sigma_x = (const float*)d_in[3];
    const float* sigma_y = (const float*)d_in[4];
    const float* weights = (const float*)d_in[5];
    float* out = (float*)d_out;

    float* scale = (float*)d_ws;                          // 4 KB
    float* xT    = (float*)((char*)d_ws + 4096);          // 6.3 MB
    float* part  = xT + (size_t)KK * BB;                  // 50.3 MB
    const size_t need = 4096 +
        sizeof(float) * ((size_t)KK * BB + (size_t)KSR * BB * NN);

    if (ws_size >= need) {
        scale_kernel<<<(NN + 255) / 256, 256, 0, stream>>>(mu_x, mu_y, sigma_x, sigma_y, scale);
        xpose_kernel<<<KK / 64, 256, 0, stream>>>(x, xT);
        main_pipe<<<KSR * BSPLIT, 256, 0, stream>>>(weights, xT, scale,
                                                    mu_x, mu_y, sigma_x, sigma_y, part);
        reduce_kernel<<<BB * NN / 128, 256, 0, stream>>>(part, out);
    } else {
        hipMemsetAsync(d_out, 0, (size_t)out_size * sizeof(float), stream);
        dim3 grid(NROWS / 2, 4);
        main_fallback<<<grid, 256, 0, stream>>>(weights, x,
                                                mu_x, mu_y, sigma_x, sigma_y, out);
    }
}

// Round 15
// 73.034 us; speedup vs baseline: 1.3166x; 1.3166x over previous
//
#include <hip/hip_runtime.h>

#define BB 32
#define CC 3
#define HH 128
#define WW 128
#define NN 1024
#define KK (CC*HH*WW)        // 49152
#define NROWS (CC*HH)        // 384
#define KSR NROWS            // 384 split-K groups (1 row each)
#define BH 16                // batches per block
#define BSPLIT (BB/BH)       // 2
#define WCH 4                // w-columns per register chunk (R8-proven)
#define NCH (WW/WCH)         // 32 chunks per row
#define SG 8                 // s-groups in fused reduce
#define STEP (1.0f/127.0f)

// ---- per-neuron normalization scale: scale[n] = sqrt(H*W/(Sx*Sy)) ----
__global__ void scale_kernel(const float* __restrict__ mu_x,
                             const float* __restrict__ mu_y,
                             const float* __restrict__ sigma_x,
                             const float* __restrict__ sigma_y,
                             float* __restrict__ scale) {
    int n = blockIdx.x * blockDim.x + threadIdx.x;
    if (n >= NN) return;
    float mux = mu_x[n], muy = mu_y[n];
    float isx = 1.0f / sigma_x[n], isy = 1.0f / sigma_y[n];
    float Sx = 0.f, Sy = 0.f;
    for (int i = 0; i < WW; ++i) {
        float dx = (i * STEP - mux) * isx;
        Sx += __expf(-dx * dx);
        float dy = (i * STEP - muy) * isy;
        Sy += __expf(-dy * dy);
    }
    scale[n] = sqrtf((float)(HH * WW) / (Sx * Sy));
}

// ---- transpose x[B,K] -> xT[K,B] (proven R1 kernel) ----
__global__ void xpose_kernel(const float* __restrict__ x, float* __restrict__ xT) {
    __shared__ float tile[64][BB + 1];
    int k0 = blockIdx.x * 64;
    int lane = threadIdx.x & 63;   // k within tile
    int bgrp = threadIdx.x >> 6;   // 0..3
#pragma unroll
    for (int i = 0; i < 8; ++i) {
        int b = bgrp * 8 + i;
        tile[lane][b] = x[(size_t)b * KK + k0 + lane];
    }
    __syncthreads();
    int b = threadIdx.x & 31;
    int kk0 = threadIdx.x >> 5;    // 0..7
#pragma unroll
    for (int i = 0; i < 8; ++i) {
        int kk = i * 8 + kk0;
        xT[(size_t)(k0 + kk) * BB + b] = tile[kk][b];
    }
}

// ---- main (R8-proven, best = 74.2 us): zero-LDS register pipeline ----
// block = (row g, batch-half b0); wave owns a 256-n slice; lane owns 4 n.
// Weights double-buffered in VGPRs (compiler-exact counted vmcnt waits);
// x read as block-uniform float4 from xT.
__global__ __launch_bounds__(256) void main_pipe(
    const float* __restrict__ weights,
    const float* __restrict__ xT,
    const float* __restrict__ scale,
    const float* __restrict__ mu_x, const float* __restrict__ mu_y,
    const float* __restrict__ sigma_x, const float* __restrict__ sigma_y,
    float* __restrict__ part)
{
    const int tid  = threadIdx.x;
    const int wv   = tid >> 6;
    const int lane = tid & 63;

    // XCD swizzle: the 2 batch-half siblings of a row -> same XCD, adjacent.
    const int d    = blockIdx.x;             // 0..767
    const int xcd  = d & 7;
    const int slot = d >> 3;                 // 0..95
    const int g    = xcd * (KSR / 8) + (slot >> 1);   // 0..383
    const int b0   = (slot & 1) * BH;
    const int r    = g;
    const int h    = r & (HH - 1);
    const int nq   = wv * 64 + lane;         // float4 index into n-arrays

    const float4 mux = ((const float4*)mu_x)[nq];
    const float4 sx4 = ((const float4*)sigma_x)[nq];
    const float4 muy = ((const float4*)mu_y)[nq];
    const float4 sy4 = ((const float4*)sigma_y)[nq];
    const float4 sc4 = ((const float4*)scale)[nq];

    float4 ax, axs, Bf, gyrow;
    ax.x = -0.5f/(sx4.x*sx4.x); ax.y = -0.5f/(sx4.y*sx4.y);
    ax.z = -0.5f/(sx4.z*sx4.z); ax.w = -0.5f/(sx4.w*sx4.w);
    axs.x = ax.x*STEP; axs.y = ax.y*STEP; axs.z = ax.z*STEP; axs.w = ax.w*STEP;
    Bf.x = __expf(2.f*axs.x*STEP); Bf.y = __expf(2.f*axs.y*STEP);
    Bf.z = __expf(2.f*axs.z*STEP); Bf.w = __expf(2.f*axs.w*STEP);
    {   // gy[h]*scale inline (no table)
        const float hp = h * STEP;
        float ayc, dd;
        ayc = -0.5f/(sy4.x*sy4.x); dd = hp-muy.x; gyrow.x = __expf(ayc*dd*dd)*sc4.x;
        ayc = -0.5f/(sy4.y*sy4.y); dd = hp-muy.y; gyrow.y = __expf(ayc*dd*dd)*sc4.y;
        ayc = -0.5f/(sy4.z*sy4.z); dd = hp-muy.z; gyrow.z = __expf(ayc*dd*dd)*sc4.z;
        ayc = -0.5f/(sy4.w*sy4.w); dd = hp-muy.w; gyrow.w = __expf(ayc*dd*dd)*sc4.w;
    }

    const float* wbase = weights + (size_t)r * WW * NN + nq * 4;
    const float4* xr4  = (const float4*)xT + (size_t)r * (WW * BB / 4) + (b0 >> 2);
    // per w: xr4[w*8 + q], q = 0..3 (16 batches)

    float4 wR[2][4];                          // double-buffered weight quads
#define WLOAD(BUF, C)                                                   \
    {                                                                   \
        _Pragma("unroll")                                               \
        for (int i = 0; i < 4; ++i)                                     \
            wR[BUF][i] = *(const float4*)(wbase + (size_t)((C)*WCH + i) * NN); \
    }

    float4 acc[BH];
#pragma unroll
    for (int b = 0; b < BH; ++b) acc[b] = make_float4(0.f, 0.f, 0.f, 0.f);

    float4 g4, r4;
    auto resync = [&](int w0) {              // fresh exps, span <= 16 w
        const float w0s = (float)w0 * STEP;
        float dd;
        dd = w0s - mux.x; g4.x = __expf(ax.x*dd*dd)*gyrow.x; r4.x = __expf(axs.x*(2.f*dd+STEP));
        dd = w0s - mux.y; g4.y = __expf(ax.y*dd*dd)*gyrow.y; r4.y = __expf(axs.y*(2.f*dd+STEP));
        dd = w0s - mux.z; g4.z = __expf(ax.z*dd*dd)*gyrow.z; r4.z = __expf(axs.z*(2.f*dd+STEP));
        dd = w0s - mux.w; g4.w = __expf(ax.w*dd*dd)*gyrow.w; r4.w = __expf(axs.w*(2.f*dd+STEP));
    };

#define FMAQ(XQ, A0)                                                    \
    {                                                                   \
        acc[A0+0].x = fmaf(XQ.x, t.x, acc[A0+0].x);                     \
        acc[A0+0].y = fmaf(XQ.x, t.y, acc[A0+0].y);                     \
        acc[A0+0].z = fmaf(XQ.x, t.z, acc[A0+0].z);                     \
        acc[A0+0].w = fmaf(XQ.x, t.w, acc[A0+0].w);                     \
        acc[A0+1].x = fmaf(XQ.y, t.x, acc[A0+1].x);                     \
        acc[A0+1].y = fmaf(XQ.y, t.y, acc[A0+1].y);                     \
        acc[A0+1].z = fmaf(XQ.y, t.z, acc[A0+1].z);                     \
        acc[A0+1].w = fmaf(XQ.y, t.w, acc[A0+1].w);                     \
        acc[A0+2].x = fmaf(XQ.z, t.x, acc[A0+2].x);                     \
        acc[A0+2].y = fmaf(XQ.z, t.y, acc[A0+2].y);                     \
        acc[A0+2].z = fmaf(XQ.z, t.z, acc[A0+2].z);                     \
        acc[A0+2].w = fmaf(XQ.z, t.w, acc[A0+2].w);                     \
        acc[A0+3].x = fmaf(XQ.w, t.x, acc[A0+3].x);                     \
        acc[A0+3].y = fmaf(XQ.w, t.y, acc[A0+3].y);                     \
        acc[A0+3].z = fmaf(XQ.w, t.z, acc[A0+3].z);                     \
        acc[A0+3].w = fmaf(XQ.w, t.w, acc[A0+3].w);                     \
    }

#define CHUNK(BUF, C)                                                   \
    {                                                                   \
        if (((C) & 3) == 0) resync((C) * WCH);                          \
        _Pragma("unroll")                                               \
        for (int i = 0; i < 4; ++i) {                                   \
            const int w = (C) * WCH + i;                                \
            const float4 xq0 = xr4[w*8 + 0];                            \
            const float4 xq1 = xr4[w*8 + 1];                            \
            const float4 xq2 = xr4[w*8 + 2];                            \
            const float4 xq3 = xr4[w*8 + 3];                            \
            const float4 wt  = wR[BUF][i];                              \
            float4 t;                                                   \
            t.x = g4.x * wt.x; t.y = g4.y * wt.y;                       \
            t.z = g4.z * wt.z; t.w = g4.w * wt.w;                       \
            FMAQ(xq0, 0)                                                \
            FMAQ(xq1, 4)                                                \
            FMAQ(xq2, 8)                                                \
            FMAQ(xq3, 12)                                               \
            g4.x *= r4.x; g4.y *= r4.y; g4.z *= r4.z; g4.w *= r4.w;     \
            r4.x *= Bf.x; r4.y *= Bf.y; r4.z *= Bf.z; r4.w *= Bf.w;     \
        }                                                               \
    }

    WLOAD(0, 0);
    for (int c = 0; c < NCH; c += 2) {
        WLOAD(1, c + 1);                     // prefetch next chunk (regs)
        CHUNK(0, c);                         // compute current
        if (c + 2 < NCH) WLOAD(0, c + 2);
        CHUNK(1, c + 1);
    }
#undef CHUNK
#undef FMAQ
#undef WLOAD

    // coalesced float4 stores into this block's private partial slice
    float* pp = part + ((size_t)g * BB + b0) * NN + (tid << 2);
#pragma unroll
    for (int b = 0; b < BH; ++b)
        *(float4*)(pp + (size_t)b * NN) = acc[b];
}

// ---- fused reduce: out[cell] = sum over 384 slices, one kernel (R14-proven) ----
// 256 blocks x 256 threads; block owns 32 cell-quads; thread sums 48 slices.
__global__ __launch_bounds__(256) void reduce_kernel(const float* __restrict__ part,
                                                     float* __restrict__ out) {
    __shared__ float4 buf[SG][32];
    const int t    = threadIdx.x;
    const int qi   = t & 31;                  // quad within block
    const int sgrp = t >> 5;                  // 0..7
    const int cq   = blockIdx.x * 32 + qi;    // 0..8191 cell-quads
    const int s0   = sgrp * (KSR / SG);       // 48 slices per group
    float4 a = make_float4(0.f, 0.f, 0.f, 0.f);
#pragma unroll 6
    for (int s = 0; s < KSR / SG; ++s) {
        const float4 v = *(const float4*)(part + (size_t)(s0 + s) * (BB * NN) + cq * 4);
        a.x += v.x; a.y += v.y; a.z += v.z; a.w += v.w;
    }
    buf[sgrp][qi] = a;
    __syncthreads();
    if (t < 32) {
        float4 r = buf[0][t];
#pragma unroll
        for (int sgi = 1; sgi < SG; ++sgi) {
            const float4 v = buf[sgi][t];
            r.x += v.x; r.y += v.y; r.z += v.z; r.w += v.w;
        }
        *(float4*)(out + (size_t)(blockIdx.x * 32 + t) * 4) = r;
    }
}

// ---- fallback (atomic, self-contained) — proven R3 structure ----
__global__ __launch_bounds__(256) void main_fallback(
    const float* __restrict__ weights,
    const float* __restrict__ x,
    const float* __restrict__ mu_x, const float* __restrict__ mu_y,
    const float* __restrict__ sigma_x, const float* __restrict__ sigma_y,
    float* __restrict__ dst)
{
    __shared__ float tile[2][WW][8];
    const int tid = threadIdx.x;
    const int g   = blockIdx.x;
    const int b0  = blockIdx.y * 8;
    const int r0  = g * 2;

    {
        const int b = tid & 7;
        const int c = tid >> 3;
        const float* xp = x + (size_t)(b0 + b) * KK + (size_t)r0 * WW + c * 8;
        const float4 v0 = ((const float4*)xp)[0];
        const float4 v1 = ((const float4*)xp)[1];
        const int row = (c * 8) >> 7;
        const int w   = (c * 8) & (WW - 1);
        tile[row][w+0][b] = v0.x; tile[row][w+1][b] = v0.y;
        tile[row][w+2][b] = v0.z; tile[row][w+3][b] = v0.w;
        tile[row][w+4][b] = v1.x; tile[row][w+5][b] = v1.y;
        tile[row][w+6][b] = v1.z; tile[row][w+7][b] = v1.w;
    }

    float4 mux4 = ((const float4*)mu_x)[tid];
    float4 muy4 = ((const float4*)mu_y)[tid];
    float4 sx4  = ((const float4*)sigma_x)[tid];
    float4 sy4  = ((const float4*)sigma_y)[tid];
    float4 ax4, ay4, sc4;
    ax4.x=-0.5f/(sx4.x*sx4.x); ax4.y=-0.5f/(sx4.y*sx4.y);
    ax4.z=-0.5f/(sx4.z*sx4.z); ax4.w=-0.5f/(sx4.w*sx4.w);
    ay4.x=-0.5f/(sy4.x*sy4.x); ay4.y=-0.5f/(sy4.y*sy4.y);
    ay4.z=-0.5f/(sy4.z*sy4.z); ay4.w=-0.5f/(sy4.w*sy4.w);
    {
        float Sx[4]={0,0,0,0}, Sy[4]={0,0,0,0};
        for (int i = 0; i < WW; ++i) {
            float pp = i * STEP, dd;
            dd=pp-mux4.x; Sx[0]+=__expf(2.f*ax4.x*dd*dd);
            dd=pp-mux4.y; Sx[1]+=__expf(2.f*ax4.y*dd*dd);
            dd=pp-mux4.z; Sx[2]+=__expf(2.f*ax4.z*dd*dd);
            dd=pp-mux4.w; Sx[3]+=__expf(2.f*ax4.w*dd*dd);
            dd=pp-muy4.x; Sy[0]+=__expf(2.f*ay4.x*dd*dd);
            dd=pp-muy4.y; Sy[1]+=__expf(2.f*ay4.y*dd*dd);
            dd=pp-muy4.z; Sy[2]+=__expf(2.f*ay4.z*dd*dd);
            dd=pp-muy4.w; Sy[3]+=__expf(2.f*ay4.w*dd*dd);
        }
        sc4.x = sqrtf((float)(HH*WW)/(Sx[0]*Sy[0]));
        sc4.y = sqrtf((float)(HH*WW)/(Sx[1]*Sy[1]));
        sc4.z = sqrtf((float)(HH*WW)/(Sx[2]*Sy[2]));
        sc4.w = sqrtf((float)(HH*WW)/(Sx[3]*Sy[3]));
    }
    __syncthreads();

    float acc[8][4];
#pragma unroll
    for (int b = 0; b < 8; ++b)
        acc[b][0] = acc[b][1] = acc[b][2] = acc[b][3] = 0.f;

#pragma unroll
    for (int rr = 0; rr < 2; ++rr) {
        const int rrow = r0 + rr;
        const int hh = rrow & (HH - 1);
        float4 gys;
        {
            float hp = hh * STEP, dd;
            dd=hp-muy4.x; gys.x = __expf(ay4.x*dd*dd) * sc4.x;
            dd=hp-muy4.y; gys.y = __expf(ay4.y*dd*dd) * sc4.y;
            dd=hp-muy4.z; gys.z = __expf(ay4.z*dd*dd) * sc4.z;
            dd=hp-muy4.w; gys.w = __expf(ay4.w*dd*dd) * sc4.w;
        }
        const float4* wp = (const float4*)(weights + (size_t)rrow * WW * NN) + tid;
        float racc[8][4];
#pragma unroll
        for (int b = 0; b < 8; ++b)
            racc[b][0] = racc[b][1] = racc[b][2] = racc[b][3] = 0.f;
        for (int w = 0; w < WW; ++w) {
            const float4 wt = wp[(size_t)w * (NN/4)];
            float pp = w * STEP, dd;
            float4 t;
            dd=pp-mux4.x; t.x = __expf(ax4.x*dd*dd) * wt.x;
            dd=pp-mux4.y; t.y = __expf(ax4.y*dd*dd) * wt.y;
            dd=pp-mux4.z; t.z = __expf(ax4.z*dd*dd) * wt.z;
            dd=pp-mux4.w; t.w = __expf(ax4.w*dd*dd) * wt.w;
            const float4* trp = (const float4*)&tile[rr][w][0];
            float xs[8];
            ((float4*)xs)[0] = trp[0]; ((float4*)xs)[1] = trp[1];
#pragma unroll
            for (int b = 0; b < 8; ++b) {
                racc[b][0] = fmaf(xs[b], t.x, racc[b][0]);
                racc[b][1] = fmaf(xs[b], t.y, racc[b][1]);
                racc[b][2] = fmaf(xs[b], t.z, racc[b][2]);
                racc[b][3] = fmaf(xs[b], t.w, racc[b][3]);
            }
        }
#pragma unroll
        for (int b = 0; b < 8; ++b) {
            acc[b][0] = fmaf(gys.x, racc[b][0], acc[b][0]);
            acc[b][1] = fmaf(gys.y, racc[b][1], acc[b][1]);
            acc[b][2] = fmaf(gys.z, racc[b][2], acc[b][2]);
            acc[b][3] = fmaf(gys.w, racc[b][3], acc[b][3]);
        }
    }

    float* op = dst + (size_t)b0 * NN + tid * 4;
#pragma unroll
    for (int b = 0; b < 8; ++b) {
        atomicAdd(op + (size_t)b * NN + 0, acc[b][0]);
        atomicAdd(op + (size_t)b * NN + 1, acc[b][1]);
        atomicAdd(op + (size_t)b * NN + 2, acc[b][2]);
        atomicAdd(op + (size_t)b * NN + 3, acc[b][3]);
    }
}

extern "C" void kernel_launch(void* const* d_in, const int* in_sizes, int n_in,
                              void* d_out, int out_size, void* d_ws, size_t ws_size,
                              hipStream_t stream) {
    const float* x       = (const float*)d_in[0];
    const float* mu_x    = (const float*)d_in[1];
    const float* mu_y    = (const float*)d_in[2];
    const float* sigma_x = (const float*)d_in[3];
    const float* sigma_y = (const float*)d_in[4];
    const float* weights = (const float*)d_in[5];
    float* out = (float*)d_out;

    float* scale = (float*)d_ws;                          // 4 KB
    float* xT    = (float*)((char*)d_ws + 4096);          // 6.3 MB
    float* part  = xT + (size_t)KK * BB;                  // 50.3 MB
    const size_t need = 4096 +
        sizeof(float) * ((size_t)KK * BB + (size_t)KSR * BB * NN);

    if (ws_size >= need) {
        scale_kernel<<<(NN + 255) / 256, 256, 0, stream>>>(mu_x, mu_y, sigma_x, sigma_y, scale);
        xpose_kernel<<<KK / 64, 256, 0, stream>>>(x, xT);
        main_pipe<<<KSR * BSPLIT, 256, 0, stream>>>(weights, xT, scale,
                                                    mu_x, mu_y, sigma_x, sigma_y, part);
        reduce_kernel<<<BB * NN / 128, 256, 0, stream>>>(part, out);
    } else {
        hipMemsetAsync(d_out, 0, (size_t)out_size * sizeof(float), stream);
        dim3 grid(NROWS / 2, 4);
        main_fallback<<<grid, 256, 0, stream>>>(weights, x,
                                                mu_x, mu_y, sigma_x, sigma_y, out);
    }
}